// Round 3
// baseline (265.505 us; speedup 1.0000x reference)
//
#include <hip/hip_runtime.h>
#include <hip/hip_bf16.h>
#include <cstdint>

using bf16   = __bf16;
using bf16x4 = __attribute__((ext_vector_type(4))) __bf16;
using bf16x8 = __attribute__((ext_vector_type(8))) __bf16;
using f32x4  = __attribute__((ext_vector_type(4))) float;

#define MFMA16(a, b, c) __builtin_amdgcn_mfma_f32_16x16x32_bf16((a), (b), (c), 0, 0, 0)

// async global->LDS, 16B per lane; LDS dest = wave-uniform base + lane*16
__device__ __forceinline__ void load_lds16(const bf16* g, bf16* l) {
    __builtin_amdgcn_global_load_lds(
        (const __attribute__((address_space(1))) void*)g,
        (__attribute__((address_space(3))) void*)l, 16, 0, 0);
}

// ---------------- cast fp32 -> bf16 (scale folded) ----------------
__global__ __launch_bounds__(256) void cast_f32_bf16(const float* __restrict__ src,
                                                     bf16* __restrict__ dst, int n4,
                                                     float scale) {
    int i = blockIdx.x * blockDim.x + threadIdx.x;
    if (i < n4) {
        float4 v = reinterpret_cast<const float4*>(src)[i];
        bf16x4 o;
        o[0] = (bf16)(v.x * scale); o[1] = (bf16)(v.y * scale);
        o[2] = (bf16)(v.z * scale); o[3] = (bf16)(v.w * scale);
        reinterpret_cast<bf16x4*>(dst)[i] = o;
    }
}

// ---------------- fused QKV projection: y = x @ [Wq|Wk|Wv]^T ----------------
// x: [4096,1024] bf16; wb: [3072,1024] bf16. 128x128 tile, BK=64, global_load_lds.
// bx<8 -> Q [B,H,S,D]; bx<16 -> K [B,H,S,D]; else -> Vt [B,H,D,S]
__global__ __launch_bounds__(256) void qkv_gemm(const bf16* __restrict__ xb,
                                                const bf16* __restrict__ wb,
                                                bf16* __restrict__ Qo,
                                                bf16* __restrict__ Ko,
                                                bf16* __restrict__ Vt) {
    const int n0 = blockIdx.x * 128;
    const int m0 = blockIdx.y * 128;

    __shared__ __align__(16) bf16 As[128 * 64];   // 16 KB, unpadded (DMA target)
    __shared__ __align__(16) bf16 Bs[128 * 64];   // 16 KB

    const int t    = threadIdx.x;
    const int lane = t & 63;
    const int wid  = t >> 6;
    const int quad = lane >> 4;
    const int col  = lane & 15;
    const int wm   = wid & 1;      // row half
    const int wn   = wid >> 1;     // col half

    // staging geometry: chunk = 1 KB = 8 rows of 64 elems; wave wid owns chunks wid*4..wid*4+3
    const int rsub = lane >> 3;          // row within chunk
    const int csub = (lane & 7) * 8;     // col elems

    f32x4 acc[4][4] = {};

    const bf16* Ag = &xb[(size_t)(m0 + wid * 32 + rsub) * 1024 + csub];
    const bf16* Bg = &wb[(size_t)(n0 + wid * 32 + rsub) * 1024 + csub];

    for (int kc = 0; kc < 1024; kc += 64) {
        __syncthreads();
#pragma unroll
        for (int j = 0; j < 4; ++j) {
            const int c = wid * 4 + j;
            load_lds16(Ag + kc + (size_t)j * 8 * 1024, &As[c * 512]);
            load_lds16(Bg + kc + (size_t)j * 8 * 1024, &Bs[c * 512]);
        }
        __syncthreads();

#pragma unroll
        for (int ks = 0; ks < 2; ++ks) {
            bf16x8 a[4], b[4];
#pragma unroll
            for (int i = 0; i < 4; ++i) {
                a[i] = *reinterpret_cast<const bf16x8*>(
                    &As[(wm * 64 + i * 16 + col) * 64 + ks * 32 + quad * 8]);
                b[i] = *reinterpret_cast<const bf16x8*>(
                    &Bs[(wn * 64 + i * 16 + col) * 64 + ks * 32 + quad * 8]);
            }
#pragma unroll
            for (int mt = 0; mt < 4; ++mt)
#pragma unroll
                for (int nt = 0; nt < 4; ++nt)
                    acc[mt][nt] = MFMA16(a[mt], b[nt], acc[mt][nt]);
        }
    }

    // epilogue: C layout row = quad*4+reg, col = lane&15; w is block-uniform
    const int w = blockIdx.x >> 3;
#pragma unroll
    for (int mt = 0; mt < 4; ++mt) {
#pragma unroll
        for (int nt = 0; nt < 4; ++nt) {
#pragma unroll
            for (int r = 0; r < 4; ++r) {
                int m = m0 + wm * 64 + mt * 16 + quad * 4 + r;
                int n = n0 + wn * 64 + nt * 16 + col;
                int bb = m >> 11, s = m & 2047;
                int n1 = n & 1023;
                int h = n1 >> 6, d = n1 & 63;
                size_t bh = (size_t)(bb * 16 + h);
                bf16 v = (bf16)acc[mt][nt][r];
                if (w == 0)      Qo[(bh * 2048 + s) * 64 + d] = v;
                else if (w == 1) Ko[(bh * 2048 + s) * 64 + d] = v;
                else             Vt[(bh * 64 + d) * 2048 + s] = v;
            }
        }
    }
}

// ---------------- V suffix tile sums ----------------
// Tail[bh][t][d] = sum_{k >= 64t} Vt[bh][d][k], t = 1..32 (Tail[32] = 0)
__global__ __launch_bounds__(256) void tail_kernel(const bf16* __restrict__ Vt,
                                                   float* __restrict__ Tail) {
    const int bh   = blockIdx.z * 16 + blockIdx.y;
    const int dgrp = blockIdx.x;
    const int wid  = threadIdx.x >> 6;
    const int lane = threadIdx.x & 63;
    const bf16* Vg = Vt + (size_t)bh * 64 * 2048;
    float* Tg = Tail + (size_t)bh * 33 * 64;

#pragma unroll
    for (int i = 0; i < 4; ++i) {
        int d = dgrp * 16 + wid * 4 + i;
        if (lane == 0) Tg[32 * 64 + d] = 0.0f;
        float s = 0.0f;
        for (int t = 31; t >= 1; --t) {
            s += (float)Vg[(size_t)d * 2048 + t * 64 + lane];
            float r = s;
#pragma unroll
            for (int off = 32; off >= 1; off >>= 1)
                r += __shfl_xor(r, off);
            if (lane == 0) Tg[t * 64 + d] = r;
        }
    }
}

// ---------------- attention ----------------
// Q pre-scaled by log2(e)/32. Multiplicative mask: masked score=0 -> p=1, still counted.
// Above-diagonal tiles contribute Tail sums; loop only s0<=q0.
__global__ __launch_bounds__(256) void attn_kernel(const bf16* __restrict__ Q,
                                                   const bf16* __restrict__ K,
                                                   const bf16* __restrict__ Vt,
                                                   const float* __restrict__ Tail,
                                                   float* __restrict__ out) {
    const int b = blockIdx.z;
    const int h = blockIdx.y;
    const int j  = ((blockIdx.y >> 3) ^ blockIdx.z) & 1;
    const int qt = j ? (31 - (int)blockIdx.x) : (int)blockIdx.x;
    const int q0 = qt * 64;

    const int t    = threadIdx.x;
    const int lane = t & 63;
    const int wid  = t >> 6;
    const int quad = lane >> 4;
    const int col  = lane & 15;

    const int bh = b * 16 + h;
    const bf16* Qg = Q + (size_t)bh * 2048 * 64;
    const bf16* Kg = K + (size_t)bh * 2048 * 64;
    const bf16* Vg = Vt + (size_t)bh * 64 * 2048;

    __shared__ __align__(16) bf16 Ks[64 * 64];      // 8 KB, unpadded (DMA target)
    __shared__ __align__(16) bf16 Vs[64 * 64];      // 8 KB
    __shared__ __align__(16) bf16 Ps[4 * 16 * 72];  // wave-private P, padded
    bf16* Pw = &Ps[wid * 16 * 72];

    bf16x8 qf[2];
#pragma unroll
    for (int ks = 0; ks < 2; ++ks)
        qf[ks] = *reinterpret_cast<const bf16x8*>(
            &Qg[(size_t)(q0 + wid * 16 + col) * 64 + ks * 32 + quad * 8]);

    bf16x8 ones;
#pragma unroll
    for (int i = 0; i < 8; ++i) ones[i] = (bf16)1.0f;

    f32x4 o[4];
    f32x4 la;
    {
        const float tc = 64.0f * (float)(31 - qt);
#pragma unroll
        for (int r = 0; r < 4; ++r) la[r] = tc;
        const float* Tg = Tail + ((size_t)bh * 33 + qt + 1) * 64;
#pragma unroll
        for (int dt = 0; dt < 4; ++dt) {
            float tv = Tg[dt * 16 + col];
#pragma unroll
            for (int r = 0; r < 4; ++r) o[dt][r] = tv;
        }
    }

    const int qrow = q0 + wid * 16 + quad * 4;
    const int c0   = wid * 2;             // 2 chunks (1KB) per wave for each of K,V
    const int rsub = lane >> 3;
    const int csub = (lane & 7) * 8;

    for (int s0 = 0; s0 <= q0; s0 += 64) {
        __syncthreads();
#pragma unroll
        for (int jj = 0; jj < 2; ++jj) {
            const int c = c0 + jj;
            load_lds16(&Kg[(size_t)s0 * 64 + c * 512 + lane * 8], &Ks[c * 512]);
            load_lds16(&Vg[(size_t)(c * 8 + rsub) * 2048 + s0 + csub], &Vs[c * 512]);
        }
        __syncthreads();

        // S' = (Q*log2e/32) K^T
        f32x4 sv[4] = {};
#pragma unroll
        for (int ks = 0; ks < 2; ++ks) {
#pragma unroll
            for (int nt = 0; nt < 4; ++nt) {
                bf16x8 kb = *reinterpret_cast<const bf16x8*>(
                    &Ks[(nt * 16 + col) * 64 + ks * 32 + quad * 8]);
                sv[nt] = MFMA16(qf[ks], kb, sv[nt]);
            }
        }

        // multiplicative mask only on the diagonal tile
        if (s0 == q0) {
#pragma unroll
            for (int nt = 0; nt < 4; ++nt) {
                int kidx = s0 + nt * 16 + col;
#pragma unroll
                for (int r = 0; r < 4; ++r)
                    if (kidx > qrow + r) sv[nt][r] = 0.0f;
            }
        }

        // p = exp2(s') -> wave-private LDS (A-operand staging)
#pragma unroll
        for (int nt = 0; nt < 4; ++nt)
#pragma unroll
            for (int r = 0; r < 4; ++r)
                Pw[(quad * 4 + r) * 72 + nt * 16 + col] =
                    (bf16)__builtin_amdgcn_exp2f(sv[nt][r]);

#pragma unroll
        for (int g = 0; g < 2; ++g) {
            bf16x8 pa = *reinterpret_cast<const bf16x8*>(&Pw[col * 72 + g * 32 + quad * 8]);
            la = MFMA16(pa, ones, la);
#pragma unroll
            for (int dt = 0; dt < 4; ++dt) {
                bf16x8 vb = *reinterpret_cast<const bf16x8*>(
                    &Vs[(dt * 16 + col) * 64 + g * 32 + quad * 8]);
                o[dt] = MFMA16(pa, vb, o[dt]);
            }
        }
    }

#pragma unroll
    for (int r = 0; r < 4; ++r) {
        int q = qrow + r;
        float inv = __builtin_amdgcn_rcpf(la[r]);
#pragma unroll
        for (int dt = 0; dt < 4; ++dt) {
            int d = dt * 16 + col;
            out[((size_t)b * 2048 + q) * 1024 + h * 64 + d] = o[dt][r] * inv;
        }
    }
}

extern "C" void kernel_launch(void* const* d_in, const int* in_sizes, int n_in,
                              void* d_out, int out_size, void* d_ws, size_t ws_size,
                              hipStream_t stream) {
    const float* x  = (const float*)d_in[0];
    const float* Wq = (const float*)d_in[1];
    const float* Wk = (const float*)d_in[2];
    const float* Wv = (const float*)d_in[3];
    float* out = (float*)d_out;

    char* ws = (char*)d_ws;
    bf16*  xb   = (bf16*)(ws);                        // 8 MB
    bf16*  wb   = (bf16*)(ws + (size_t)(8  << 20));   // 6 MB [Wq|Wk|Wv]
    bf16*  Qb   = (bf16*)(ws + (size_t)(14 << 20));   // 8 MB [B,H,S,D] (pre-scaled)
    bf16*  Kb   = (bf16*)(ws + (size_t)(22 << 20));   // 8 MB [B,H,S,D]
    bf16*  Vtb  = (bf16*)(ws + (size_t)(30 << 20));   // 8 MB [B,H,D,S]
    float* Tail = (float*)(ws + (size_t)(38 << 20));  // 264 KB

    const float QSCALE = 1.44269504088896f / 32.0f;   // log2(e)/sqrt(E)

    cast_f32_bf16<<<4096, 256, 0, stream>>>(x, xb, 1048576, 1.0f);
    cast_f32_bf16<<<1024, 256, 0, stream>>>(Wq, wb, 262144, QSCALE);
    cast_f32_bf16<<<1024, 256, 0, stream>>>(Wk, wb + (1u << 20), 262144, 1.0f);
    cast_f32_bf16<<<1024, 256, 0, stream>>>(Wv, wb + (2u << 20), 262144, 1.0f);

    qkv_gemm<<<dim3(24, 32), 256, 0, stream>>>(xb, wb, Qb, Kb, Vtb);

    tail_kernel<<<dim3(4, 16, 2), 256, 0, stream>>>(Vtb, Tail);

    attn_kernel<<<dim3(32, 16, 2), 256, 0, stream>>>(Qb, Kb, Vtb, Tail, out);
}

// Round 4
// 244.995 us; speedup vs baseline: 1.0837x; 1.0837x over previous
//
#include <hip/hip_runtime.h>
#include <hip/hip_bf16.h>
#include <cstdint>

using bf16   = __bf16;
using bf16x4 = __attribute__((ext_vector_type(4))) __bf16;
using bf16x8 = __attribute__((ext_vector_type(8))) __bf16;
using f32x4  = __attribute__((ext_vector_type(4))) float;

#define MFMA16(a, b, c) __builtin_amdgcn_mfma_f32_16x16x32_bf16((a), (b), (c), 0, 0, 0)

// async global->LDS, 16B per lane; LDS dest = wave-uniform base + lane*16.
// Global address is PER-LANE: we exploit that to XOR-swizzle which chunk each
// lane fetches, so stride-64 LDS rows read back conflict-free.
__device__ __forceinline__ void load_lds16(const bf16* g, bf16* l) {
    __builtin_amdgcn_global_load_lds(
        (const __attribute__((address_space(1))) void*)g,
        (__attribute__((address_space(3))) void*)l, 16, 0, 0);
}

// ---------------- cast fp32 -> bf16 (scale folded) ----------------
__global__ __launch_bounds__(256) void cast_f32_bf16(const float* __restrict__ src,
                                                     bf16* __restrict__ dst, int n4,
                                                     float scale) {
    int i = blockIdx.x * blockDim.x + threadIdx.x;
    if (i < n4) {
        float4 v = reinterpret_cast<const float4*>(src)[i];
        bf16x4 o;
        o[0] = (bf16)(v.x * scale); o[1] = (bf16)(v.y * scale);
        o[2] = (bf16)(v.z * scale); o[3] = (bf16)(v.w * scale);
        reinterpret_cast<bf16x4*>(dst)[i] = o;
    }
}

// ---------------- fused QKV projection: y = x @ [Wq|Wk|Wv]^T ----------------
// LDS layout: LDS[row][cc] = global[row][cc ^ (row&7)] (8-elem chunks).
// Fragment read: chunk' = (ks*4+quad) ^ (col&7) -> 2-way bank aliasing (free).
__global__ __launch_bounds__(256) void qkv_gemm(const bf16* __restrict__ xb,
                                                const bf16* __restrict__ wb,
                                                bf16* __restrict__ Qo,
                                                bf16* __restrict__ Ko,
                                                bf16* __restrict__ Vt) {
    const int n0 = blockIdx.x * 128;
    const int m0 = blockIdx.y * 128;

    __shared__ __align__(16) bf16 As[128 * 64];   // 16 KB, unpadded (DMA target)
    __shared__ __align__(16) bf16 Bs[128 * 64];   // 16 KB

    const int t    = threadIdx.x;
    const int lane = t & 63;
    const int wid  = t >> 6;
    const int quad = lane >> 4;
    const int col  = lane & 15;
    const int wm   = wid & 1;
    const int wn   = wid >> 1;

    // staging: chunk-block = 1 KB = 8 rows x 64 elems; wave owns blocks wid*4..+3
    const int rsub = lane >> 3;                       // row within chunk-block
    const int csw  = ((lane & 7) ^ rsub) * 8;         // XOR-swizzled chunk

    f32x4 acc[4][4] = {};

    const bf16* Ag = &xb[(size_t)(m0 + wid * 32 + rsub) * 1024 + csw];
    const bf16* Bg = &wb[(size_t)(n0 + wid * 32 + rsub) * 1024 + csw];

    for (int kc = 0; kc < 1024; kc += 64) {
        __syncthreads();
#pragma unroll
        for (int j = 0; j < 4; ++j) {
            const int c = wid * 4 + j;
            load_lds16(Ag + kc + (size_t)j * 8 * 1024, &As[c * 512]);
            load_lds16(Bg + kc + (size_t)j * 8 * 1024, &Bs[c * 512]);
        }
        __syncthreads();

#pragma unroll
        for (int ks = 0; ks < 2; ++ks) {
            bf16x8 a[4], b[4];
#pragma unroll
            for (int i = 0; i < 4; ++i) {
                const int ca = ((ks * 4 + quad) ^ (col & 7)) * 8;
                a[i] = *reinterpret_cast<const bf16x8*>(
                    &As[(wm * 64 + i * 16 + col) * 64 + ca]);
                b[i] = *reinterpret_cast<const bf16x8*>(
                    &Bs[(wn * 64 + i * 16 + col) * 64 + ca]);
            }
#pragma unroll
            for (int mt = 0; mt < 4; ++mt)
#pragma unroll
                for (int nt = 0; nt < 4; ++nt)
                    acc[mt][nt] = MFMA16(a[mt], b[nt], acc[mt][nt]);
        }
    }

    const int w = blockIdx.x >> 3;
#pragma unroll
    for (int mt = 0; mt < 4; ++mt) {
#pragma unroll
        for (int nt = 0; nt < 4; ++nt) {
#pragma unroll
            for (int r = 0; r < 4; ++r) {
                int m = m0 + wm * 64 + mt * 16 + quad * 4 + r;
                int n = n0 + wn * 64 + nt * 16 + col;
                int bb = m >> 11, s = m & 2047;
                int n1 = n & 1023;
                int h = n1 >> 6, d = n1 & 63;
                size_t bh = (size_t)(bb * 16 + h);
                bf16 v = (bf16)acc[mt][nt][r];
                if (w == 0)      Qo[(bh * 2048 + s) * 64 + d] = v;
                else if (w == 1) Ko[(bh * 2048 + s) * 64 + d] = v;
                else             Vt[(bh * 64 + d) * 2048 + s] = v;
            }
        }
    }
}

// ---------------- V suffix tile sums ----------------
__global__ __launch_bounds__(256) void tail_kernel(const bf16* __restrict__ Vt,
                                                   float* __restrict__ Tail) {
    const int bh   = blockIdx.z * 16 + blockIdx.y;
    const int dgrp = blockIdx.x;
    const int wid  = threadIdx.x >> 6;
    const int lane = threadIdx.x & 63;
    const bf16* Vg = Vt + (size_t)bh * 64 * 2048;
    float* Tg = Tail + (size_t)bh * 33 * 64;

#pragma unroll
    for (int i = 0; i < 4; ++i) {
        int d = dgrp * 16 + wid * 4 + i;
        if (lane == 0) Tg[32 * 64 + d] = 0.0f;
        float s = 0.0f;
        for (int t = 31; t >= 1; --t) {
            s += (float)Vg[(size_t)d * 2048 + t * 64 + lane];
            float r = s;
#pragma unroll
            for (int off = 32; off >= 1; off >>= 1)
                r += __shfl_xor(r, off);
            if (lane == 0) Tg[t * 64 + d] = r;
        }
    }
}

// ---------------- attention ----------------
// Q pre-scaled by log2(e)/32. Multiplicative mask: masked score=0 -> p=1, still counted.
// Above-diagonal tiles contribute Tail sums; loop only s0<=q0. K/V tiles XOR-swizzled.
__global__ __launch_bounds__(256) void attn_kernel(const bf16* __restrict__ Q,
                                                   const bf16* __restrict__ K,
                                                   const bf16* __restrict__ Vt,
                                                   const float* __restrict__ Tail,
                                                   float* __restrict__ out) {
    const int b = blockIdx.z;
    const int h = blockIdx.y;
    const int j  = ((blockIdx.y >> 3) ^ blockIdx.z) & 1;
    const int qt = j ? (31 - (int)blockIdx.x) : (int)blockIdx.x;
    const int q0 = qt * 64;

    const int t    = threadIdx.x;
    const int lane = t & 63;
    const int wid  = t >> 6;
    const int quad = lane >> 4;
    const int col  = lane & 15;

    const int bh = b * 16 + h;
    const bf16* Qg = Q + (size_t)bh * 2048 * 64;
    const bf16* Kg = K + (size_t)bh * 2048 * 64;
    const bf16* Vg = Vt + (size_t)bh * 64 * 2048;

    __shared__ __align__(16) bf16 Ks[64 * 64];
    __shared__ __align__(16) bf16 Vs[64 * 64];
    __shared__ __align__(16) bf16 Ps[4 * 16 * 72];
    bf16* Pw = &Ps[wid * 16 * 72];

    bf16x8 qf[2];
#pragma unroll
    for (int ks = 0; ks < 2; ++ks)
        qf[ks] = *reinterpret_cast<const bf16x8*>(
            &Qg[(size_t)(q0 + wid * 16 + col) * 64 + ks * 32 + quad * 8]);

    bf16x8 ones;
#pragma unroll
    for (int i = 0; i < 8; ++i) ones[i] = (bf16)1.0f;

    f32x4 o[4];
    f32x4 la;
    {
        const float tc = 64.0f * (float)(31 - qt);
#pragma unroll
        for (int r = 0; r < 4; ++r) la[r] = tc;
        const float* Tg = Tail + ((size_t)bh * 33 + qt + 1) * 64;
#pragma unroll
        for (int dt = 0; dt < 4; ++dt) {
            float tv = Tg[dt * 16 + col];
#pragma unroll
            for (int r = 0; r < 4; ++r) o[dt][r] = tv;
        }
    }

    const int qrow = q0 + wid * 16 + quad * 4;
    const int c0   = wid * 2;
    const int rsub = lane >> 3;
    const int csw  = ((lane & 7) ^ rsub) * 8;   // XOR-swizzled chunk

    for (int s0 = 0; s0 <= q0; s0 += 64) {
        __syncthreads();
#pragma unroll
        for (int jj = 0; jj < 2; ++jj) {
            const int c = c0 + jj;
            load_lds16(&Kg[(size_t)s0 * 64 + c * 512 + rsub * 64 + csw], &Ks[c * 512]);
            load_lds16(&Vg[(size_t)(c * 8 + rsub) * 2048 + s0 + csw], &Vs[c * 512]);
        }
        __syncthreads();

        // S' = (Q*log2e/32) K^T
        f32x4 sv[4] = {};
#pragma unroll
        for (int ks = 0; ks < 2; ++ks) {
            const int ca = ((ks * 4 + quad) ^ (col & 7)) * 8;
#pragma unroll
            for (int nt = 0; nt < 4; ++nt) {
                bf16x8 kb = *reinterpret_cast<const bf16x8*>(
                    &Ks[(nt * 16 + col) * 64 + ca]);
                sv[nt] = MFMA16(qf[ks], kb, sv[nt]);
            }
        }

        if (s0 == q0) {
#pragma unroll
            for (int nt = 0; nt < 4; ++nt) {
                int kidx = s0 + nt * 16 + col;
#pragma unroll
                for (int r = 0; r < 4; ++r)
                    if (kidx > qrow + r) sv[nt][r] = 0.0f;
            }
        }

        // p = exp2(s') -> wave-private LDS (A-operand staging)
#pragma unroll
        for (int nt = 0; nt < 4; ++nt)
#pragma unroll
            for (int r = 0; r < 4; ++r)
                Pw[(quad * 4 + r) * 72 + nt * 16 + col] =
                    (bf16)__builtin_amdgcn_exp2f(sv[nt][r]);

#pragma unroll
        for (int g = 0; g < 2; ++g) {
            bf16x8 pa = *reinterpret_cast<const bf16x8*>(&Pw[col * 72 + g * 32 + quad * 8]);
            la = MFMA16(pa, ones, la);
            const int ca = ((g * 4 + quad) ^ (col & 7)) * 8;
#pragma unroll
            for (int dt = 0; dt < 4; ++dt) {
                bf16x8 vb = *reinterpret_cast<const bf16x8*>(
                    &Vs[(dt * 16 + col) * 64 + ca]);
                o[dt] = MFMA16(pa, vb, o[dt]);
            }
        }
    }

#pragma unroll
    for (int r = 0; r < 4; ++r) {
        int q = qrow + r;
        float inv = __builtin_amdgcn_rcpf(la[r]);
#pragma unroll
        for (int dt = 0; dt < 4; ++dt) {
            int d = dt * 16 + col;
            out[((size_t)b * 2048 + q) * 1024 + h * 64 + d] = o[dt][r] * inv;
        }
    }
}

extern "C" void kernel_launch(void* const* d_in, const int* in_sizes, int n_in,
                              void* d_out, int out_size, void* d_ws, size_t ws_size,
                              hipStream_t stream) {
    const float* x  = (const float*)d_in[0];
    const float* Wq = (const float*)d_in[1];
    const float* Wk = (const float*)d_in[2];
    const float* Wv = (const float*)d_in[3];
    float* out = (float*)d_out;

    char* ws = (char*)d_ws;
    bf16*  xb   = (bf16*)(ws);                        // 8 MB
    bf16*  wb   = (bf16*)(ws + (size_t)(8  << 20));   // 6 MB [Wq|Wk|Wv]
    bf16*  Qb   = (bf16*)(ws + (size_t)(14 << 20));   // 8 MB [B,H,S,D] (pre-scaled)
    bf16*  Kb   = (bf16*)(ws + (size_t)(22 << 20));   // 8 MB [B,H,S,D]
    bf16*  Vtb  = (bf16*)(ws + (size_t)(30 << 20));   // 8 MB [B,H,D,S]
    float* Tail = (float*)(ws + (size_t)(38 << 20));  // 264 KB

    const float QSCALE = 1.44269504088896f / 32.0f;   // log2(e)/sqrt(E)

    cast_f32_bf16<<<4096, 256, 0, stream>>>(x, xb, 1048576, 1.0f);
    cast_f32_bf16<<<1024, 256, 0, stream>>>(Wq, wb, 262144, QSCALE);
    cast_f32_bf16<<<1024, 256, 0, stream>>>(Wk, wb + (1u << 20), 262144, 1.0f);
    cast_f32_bf16<<<1024, 256, 0, stream>>>(Wv, wb + (2u << 20), 262144, 1.0f);

    qkv_gemm<<<dim3(24, 32), 256, 0, stream>>>(xb, wb, Qb, Kb, Vtb);

    tail_kernel<<<dim3(4, 16, 2), 256, 0, stream>>>(Vtb, Tail);

    attn_kernel<<<dim3(32, 16, 2), 256, 0, stream>>>(Qb, Kb, Vtb, Tail, out);
}

// Round 5
// 197.227 us; speedup vs baseline: 1.3462x; 1.2422x over previous
//
#include <hip/hip_runtime.h>
#include <hip/hip_bf16.h>
#include <cstdint>

using bf16   = __bf16;
using bf16x4 = __attribute__((ext_vector_type(4))) __bf16;
using bf16x8 = __attribute__((ext_vector_type(8))) __bf16;
using f32x4  = __attribute__((ext_vector_type(4))) float;

#define MFMA16(a, b, c) __builtin_amdgcn_mfma_f32_16x16x32_bf16((a), (b), (c), 0, 0, 0)

// async global->LDS, 16B per lane; LDS dest = wave-uniform base + lane*16.
__device__ __forceinline__ void load_lds16(const bf16* g, bf16* l) {
    __builtin_amdgcn_global_load_lds(
        (const __attribute__((address_space(1))) void*)g,
        (__attribute__((address_space(3))) void*)l, 16, 0, 0);
}

// ---------------- fused cast fp32 -> bf16 (x, Wq*scale, Wk, Wv) ----------------
__global__ __launch_bounds__(256) void cast_all(const float* __restrict__ x,
                                                const float* __restrict__ Wq,
                                                const float* __restrict__ Wk,
                                                const float* __restrict__ Wv,
                                                bf16* __restrict__ xb,
                                                bf16* __restrict__ wb,
                                                float qscale) {
    int i = blockIdx.x * 256 + threadIdx.x;   // float4 index, 1835008 total
    const float* src; bf16* dst; int off; float scale = 1.0f;
    if (i < 1048576)      { src = x;  dst = xb;              off = i; }
    else if (i < 1310720) { src = Wq; dst = wb;              off = i - 1048576; scale = qscale; }
    else if (i < 1572864) { src = Wk; dst = wb + (1u << 20); off = i - 1310720; }
    else                  { src = Wv; dst = wb + (2u << 20); off = i - 1572864; }
    float4 v = reinterpret_cast<const float4*>(src)[off];
    bf16x4 o;
    o[0] = (bf16)(v.x * scale); o[1] = (bf16)(v.y * scale);
    o[2] = (bf16)(v.z * scale); o[3] = (bf16)(v.w * scale);
    reinterpret_cast<bf16x4*>(dst)[off] = o;
}

// ---------------- fused QKV projection: y = x @ [Wq|Wk|Wv]^T ----------------
// LDS[row][cc] = global[row][cc ^ (row&7)] (8-elem chunks, XOR swizzle, conflict-free)
__global__ __launch_bounds__(256) void qkv_gemm(const bf16* __restrict__ xb,
                                                const bf16* __restrict__ wb,
                                                bf16* __restrict__ Qo,
                                                bf16* __restrict__ Ko,
                                                bf16* __restrict__ Vt) {
    const int n0 = blockIdx.x * 128;
    const int m0 = blockIdx.y * 128;

    __shared__ __align__(16) bf16 As[128 * 64];
    __shared__ __align__(16) bf16 Bs[128 * 64];

    const int t    = threadIdx.x;
    const int lane = t & 63;
    const int wid  = t >> 6;
    const int quad = lane >> 4;
    const int col  = lane & 15;
    const int wm   = wid & 1;
    const int wn   = wid >> 1;

    const int rsub = lane >> 3;
    const int csw  = ((lane & 7) ^ rsub) * 8;

    f32x4 acc[4][4] = {};

    const bf16* Ag = &xb[(size_t)(m0 + wid * 32 + rsub) * 1024 + csw];
    const bf16* Bg = &wb[(size_t)(n0 + wid * 32 + rsub) * 1024 + csw];

    for (int kc = 0; kc < 1024; kc += 64) {
        __syncthreads();
#pragma unroll
        for (int j = 0; j < 4; ++j) {
            const int c = wid * 4 + j;
            load_lds16(Ag + kc + (size_t)j * 8 * 1024, &As[c * 512]);
            load_lds16(Bg + kc + (size_t)j * 8 * 1024, &Bs[c * 512]);
        }
        __syncthreads();

#pragma unroll
        for (int ks = 0; ks < 2; ++ks) {
            bf16x8 a[4], b[4];
#pragma unroll
            for (int i = 0; i < 4; ++i) {
                const int ca = ((ks * 4 + quad) ^ (col & 7)) * 8;
                a[i] = *reinterpret_cast<const bf16x8*>(
                    &As[(wm * 64 + i * 16 + col) * 64 + ca]);
                b[i] = *reinterpret_cast<const bf16x8*>(
                    &Bs[(wn * 64 + i * 16 + col) * 64 + ca]);
            }
#pragma unroll
            for (int mt = 0; mt < 4; ++mt)
#pragma unroll
                for (int nt = 0; nt < 4; ++nt)
                    acc[mt][nt] = MFMA16(a[mt], b[nt], acc[mt][nt]);
        }
    }

    const int w = blockIdx.x >> 3;
#pragma unroll
    for (int mt = 0; mt < 4; ++mt) {
#pragma unroll
        for (int nt = 0; nt < 4; ++nt) {
#pragma unroll
            for (int r = 0; r < 4; ++r) {
                int m = m0 + wm * 64 + mt * 16 + quad * 4 + r;
                int n = n0 + wn * 64 + nt * 16 + col;
                int bb = m >> 11, s = m & 2047;
                int n1 = n & 1023;
                int h = n1 >> 6, d = n1 & 63;
                size_t bh = (size_t)(bb * 16 + h);
                bf16 v = (bf16)acc[mt][nt][r];
                if (w == 0)      Qo[(bh * 2048 + s) * 64 + d] = v;
                else if (w == 1) Ko[(bh * 2048 + s) * 64 + d] = v;
                else             Vt[(bh * 64 + d) * 2048 + s] = v;
            }
        }
    }
}

// ---------------- V suffix tile sums (parallel) ----------------
// Tail[bh][t][d] = sum_{k >= 64t} Vt[bh][d][k], t=1..32 (Tail[32]=0).
// Phase 1: 2048 independent tile-sums (8/thread, bf16x8 loads). Phase 2: 32-step scan.
__global__ __launch_bounds__(256) void tail_kernel(const bf16* __restrict__ Vt,
                                                   float* __restrict__ Tail) {
    const int bh = blockIdx.x;
    const bf16* Vg = Vt + (size_t)bh * 64 * 2048;
    float* Tg = Tail + (size_t)bh * 33 * 64;

    __shared__ float ts[64 * 33];
    const int tid = threadIdx.x;

#pragma unroll
    for (int i = 0; i < 8; ++i) {
        int task = i * 256 + tid;          // 0..2047
        int d = task >> 5, tt = task & 31;
        const bf16* p = &Vg[(size_t)d * 2048 + tt * 64];
        float s = 0.0f;
#pragma unroll
        for (int j = 0; j < 8; ++j) {
            bf16x8 v = *reinterpret_cast<const bf16x8*>(p + j * 8);
#pragma unroll
            for (int e = 0; e < 8; ++e) s += (float)v[e];
        }
        ts[d * 33 + tt] = s;
    }
    __syncthreads();

    if (tid < 64) {
        const int d = tid;
        float s = 0.0f;
        Tg[32 * 64 + d] = 0.0f;
        for (int tt = 31; tt >= 1; --tt) {
            s += ts[d * 33 + tt];
            Tg[tt * 64 + d] = s;
        }
    }
}

// ---------------- attention ----------------
// Q pre-scaled by log2(e)/32. Multiplicative mask: masked score=0 -> p=1, still counted.
// Above-diagonal tiles contribute Tail sums; loop only s0<=q0. K/V tiles XOR-swizzled.
__global__ __launch_bounds__(256) void attn_kernel(const bf16* __restrict__ Q,
                                                   const bf16* __restrict__ K,
                                                   const bf16* __restrict__ Vt,
                                                   const float* __restrict__ Tail,
                                                   float* __restrict__ out) {
    const int b = blockIdx.z;
    const int h = blockIdx.y;
    const int j  = ((blockIdx.y >> 3) ^ blockIdx.z) & 1;
    const int qt = j ? (31 - (int)blockIdx.x) : (int)blockIdx.x;
    const int q0 = qt * 64;

    const int t    = threadIdx.x;
    const int lane = t & 63;
    const int wid  = t >> 6;
    const int quad = lane >> 4;
    const int col  = lane & 15;

    const int bh = b * 16 + h;
    const bf16* Qg = Q + (size_t)bh * 2048 * 64;
    const bf16* Kg = K + (size_t)bh * 2048 * 64;
    const bf16* Vg = Vt + (size_t)bh * 64 * 2048;

    __shared__ __align__(16) bf16 Ks[64 * 64];
    __shared__ __align__(16) bf16 Vs[64 * 64];
    __shared__ __align__(16) bf16 Ps[4 * 16 * 72];
    bf16* Pw = &Ps[wid * 16 * 72];

    bf16x8 qf[2];
#pragma unroll
    for (int ks = 0; ks < 2; ++ks)
        qf[ks] = *reinterpret_cast<const bf16x8*>(
            &Qg[(size_t)(q0 + wid * 16 + col) * 64 + ks * 32 + quad * 8]);

    bf16x8 ones;
#pragma unroll
    for (int i = 0; i < 8; ++i) ones[i] = (bf16)1.0f;

    f32x4 o[4];
    f32x4 la;
    {
        const float tc = 64.0f * (float)(31 - qt);
#pragma unroll
        for (int r = 0; r < 4; ++r) la[r] = tc;
        const float* Tg = Tail + ((size_t)bh * 33 + qt + 1) * 64;
#pragma unroll
        for (int dt = 0; dt < 4; ++dt) {
            float tv = Tg[dt * 16 + col];
#pragma unroll
            for (int r = 0; r < 4; ++r) o[dt][r] = tv;
        }
    }

    const int qrow = q0 + wid * 16 + quad * 4;
    const int c0   = wid * 2;
    const int rsub = lane >> 3;
    const int csw  = ((lane & 7) ^ rsub) * 8;

    for (int s0 = 0; s0 <= q0; s0 += 64) {
        __syncthreads();
#pragma unroll
        for (int jj = 0; jj < 2; ++jj) {
            const int c = c0 + jj;
            load_lds16(&Kg[(size_t)s0 * 64 + c * 512 + rsub * 64 + csw], &Ks[c * 512]);
            load_lds16(&Vg[(size_t)(c * 8 + rsub) * 2048 + s0 + csw], &Vs[c * 512]);
        }
        __syncthreads();

        f32x4 sv[4] = {};
#pragma unroll
        for (int ks = 0; ks < 2; ++ks) {
            const int ca = ((ks * 4 + quad) ^ (col & 7)) * 8;
#pragma unroll
            for (int nt = 0; nt < 4; ++nt) {
                bf16x8 kb = *reinterpret_cast<const bf16x8*>(
                    &Ks[(nt * 16 + col) * 64 + ca]);
                sv[nt] = MFMA16(qf[ks], kb, sv[nt]);
            }
        }

        if (s0 == q0) {
#pragma unroll
            for (int nt = 0; nt < 4; ++nt) {
                int kidx = s0 + nt * 16 + col;
#pragma unroll
                for (int r = 0; r < 4; ++r)
                    if (kidx > qrow + r) sv[nt][r] = 0.0f;
            }
        }

#pragma unroll
        for (int nt = 0; nt < 4; ++nt)
#pragma unroll
            for (int r = 0; r < 4; ++r)
                Pw[(quad * 4 + r) * 72 + nt * 16 + col] =
                    (bf16)__builtin_amdgcn_exp2f(sv[nt][r]);

#pragma unroll
        for (int g = 0; g < 2; ++g) {
            bf16x8 pa = *reinterpret_cast<const bf16x8*>(&Pw[col * 72 + g * 32 + quad * 8]);
            la = MFMA16(pa, ones, la);
            const int ca = ((g * 4 + quad) ^ (col & 7)) * 8;
#pragma unroll
            for (int dt = 0; dt < 4; ++dt) {
                bf16x8 vb = *reinterpret_cast<const bf16x8*>(
                    &Vs[(dt * 16 + col) * 64 + ca]);
                o[dt] = MFMA16(pa, vb, o[dt]);
            }
        }
    }

#pragma unroll
    for (int r = 0; r < 4; ++r) {
        int q = qrow + r;
        float inv = __builtin_amdgcn_rcpf(la[r]);
#pragma unroll
        for (int dt = 0; dt < 4; ++dt) {
            int d = dt * 16 + col;
            out[((size_t)b * 2048 + q) * 1024 + h * 64 + d] = o[dt][r] * inv;
        }
    }
}

extern "C" void kernel_launch(void* const* d_in, const int* in_sizes, int n_in,
                              void* d_out, int out_size, void* d_ws, size_t ws_size,
                              hipStream_t stream) {
    const float* x  = (const float*)d_in[0];
    const float* Wq = (const float*)d_in[1];
    const float* Wk = (const float*)d_in[2];
    const float* Wv = (const float*)d_in[3];
    float* out = (float*)d_out;

    char* ws = (char*)d_ws;
    bf16*  xb   = (bf16*)(ws);                        // 8 MB
    bf16*  wb   = (bf16*)(ws + (size_t)(8  << 20));   // 6 MB [Wq|Wk|Wv]
    bf16*  Qb   = (bf16*)(ws + (size_t)(14 << 20));   // 8 MB [B,H,S,D] (pre-scaled)
    bf16*  Kb   = (bf16*)(ws + (size_t)(22 << 20));   // 8 MB [B,H,S,D]
    bf16*  Vtb  = (bf16*)(ws + (size_t)(30 << 20));   // 8 MB [B,H,D,S]
    float* Tail = (float*)(ws + (size_t)(38 << 20));  // 264 KB

    const float QSCALE = 1.44269504088896f / 32.0f;   // log2(e)/sqrt(E)

    cast_all<<<7168, 256, 0, stream>>>(x, Wq, Wk, Wv, xb, wb, QSCALE);

    qkv_gemm<<<dim3(24, 32), 256, 0, stream>>>(xb, wb, Qb, Kb, Vtb);

    tail_kernel<<<32, 256, 0, stream>>>(Vtb, Tail);

    attn_kernel<<<dim3(32, 16, 2), 256, 0, stream>>>(Qb, Kb, Vtb, Tail, out);
}

// Round 6
// 191.699 us; speedup vs baseline: 1.3850x; 1.0288x over previous
//
#include <hip/hip_runtime.h>
#include <hip/hip_bf16.h>
#include <cstdint>

using bf16   = __bf16;
using bf16x4 = __attribute__((ext_vector_type(4))) __bf16;
using bf16x8 = __attribute__((ext_vector_type(8))) __bf16;
using f32x4  = __attribute__((ext_vector_type(4))) float;

#define MFMA16(a, b, c) __builtin_amdgcn_mfma_f32_16x16x32_bf16((a), (b), (c), 0, 0, 0)

// async global->LDS, 16B per lane; LDS dest = wave-uniform base + lane*16.
__device__ __forceinline__ void load_lds16(const bf16* g, bf16* l) {
    __builtin_amdgcn_global_load_lds(
        (const __attribute__((address_space(1))) void*)g,
        (__attribute__((address_space(3))) void*)l, 16, 0, 0);
}

// ---------------- fused cast fp32 -> bf16 (x, Wq*scale, Wk, Wv) ----------------
__global__ __launch_bounds__(256) void cast_all(const float* __restrict__ x,
                                                const float* __restrict__ Wq,
                                                const float* __restrict__ Wk,
                                                const float* __restrict__ Wv,
                                                bf16* __restrict__ xb,
                                                bf16* __restrict__ wb,
                                                float qscale) {
    int i = blockIdx.x * 256 + threadIdx.x;   // float4 index, 1835008 total
    const float* src; bf16* dst; int off; float scale = 1.0f;
    if (i < 1048576)      { src = x;  dst = xb;              off = i; }
    else if (i < 1310720) { src = Wq; dst = wb;              off = i - 1048576; scale = qscale; }
    else if (i < 1572864) { src = Wk; dst = wb + (1u << 20); off = i - 1310720; }
    else                  { src = Wv; dst = wb + (2u << 20); off = i - 1572864; }
    float4 v = reinterpret_cast<const float4*>(src)[off];
    bf16x4 o;
    o[0] = (bf16)(v.x * scale); o[1] = (bf16)(v.y * scale);
    o[2] = (bf16)(v.z * scale); o[3] = (bf16)(v.w * scale);
    reinterpret_cast<bf16x4*>(dst)[off] = o;
}

// ---------------- fused QKV projection: y = x @ [Wq|Wk|Wv]^T ----------------
// 128x64 tiles (M x N), BK=64 -> 1536 blocks = 6/CU for barrier-drain overlap.
// LDS[row][cc] = global[row][cc ^ (row&7)] (8-elem chunks, conflict-free readback)
__global__ __launch_bounds__(256) void qkv_gemm(const bf16* __restrict__ xb,
                                                const bf16* __restrict__ wb,
                                                bf16* __restrict__ Qo,
                                                bf16* __restrict__ Ko,
                                                bf16* __restrict__ Vt) {
    const int n0 = blockIdx.x * 64;
    const int m0 = blockIdx.y * 128;

    __shared__ __align__(16) bf16 As[128 * 64];   // 16 KB
    __shared__ __align__(16) bf16 Bs[64 * 64];    // 8 KB

    const int t    = threadIdx.x;
    const int lane = t & 63;
    const int wid  = t >> 6;
    const int quad = lane >> 4;
    const int col  = lane & 15;
    const int wm   = wid & 1;      // M half (64)
    const int wn   = wid >> 1;     // N half (32)

    const int rsub = lane >> 3;
    const int csw  = ((lane & 7) ^ rsub) * 8;

    f32x4 acc[4][2] = {};

    const bf16* Ag = &xb[(size_t)(m0 + rsub) * 1024 + csw];
    const bf16* Bg = &wb[(size_t)(n0 + rsub) * 1024 + csw];

    for (int kc = 0; kc < 1024; kc += 64) {
        __syncthreads();
#pragma unroll
        for (int j = 0; j < 4; ++j) {
            const int c = wid * 4 + j;           // 16 A chunk-blocks
            load_lds16(Ag + kc + (size_t)c * 8 * 1024, &As[c * 512]);
        }
#pragma unroll
        for (int j = 0; j < 2; ++j) {
            const int c = wid * 2 + j;           // 8 B chunk-blocks
            load_lds16(Bg + kc + (size_t)c * 8 * 1024, &Bs[c * 512]);
        }
        __syncthreads();

#pragma unroll
        for (int ks = 0; ks < 2; ++ks) {
            const int ca = ((ks * 4 + quad) ^ (col & 7)) * 8;
            bf16x8 a[4], b[2];
#pragma unroll
            for (int i = 0; i < 4; ++i)
                a[i] = *reinterpret_cast<const bf16x8*>(
                    &As[(wm * 64 + i * 16 + col) * 64 + ca]);
#pragma unroll
            for (int i = 0; i < 2; ++i)
                b[i] = *reinterpret_cast<const bf16x8*>(
                    &Bs[(wn * 32 + i * 16 + col) * 64 + ca]);
#pragma unroll
            for (int mt = 0; mt < 4; ++mt)
#pragma unroll
                for (int nt = 0; nt < 2; ++nt)
                    acc[mt][nt] = MFMA16(a[mt], b[nt], acc[mt][nt]);
        }
    }

    const int w = blockIdx.x >> 4;   // 16 n-tiles per 1024 outputs
#pragma unroll
    for (int mt = 0; mt < 4; ++mt) {
#pragma unroll
        for (int nt = 0; nt < 2; ++nt) {
#pragma unroll
            for (int r = 0; r < 4; ++r) {
                int m = m0 + wm * 64 + mt * 16 + quad * 4 + r;
                int n = n0 + wn * 32 + nt * 16 + col;
                int bb = m >> 11, s = m & 2047;
                int n1 = n & 1023;
                int h = n1 >> 6, d = n1 & 63;
                size_t bh = (size_t)(bb * 16 + h);
                bf16 v = (bf16)acc[mt][nt][r];
                if (w == 0)      Qo[(bh * 2048 + s) * 64 + d] = v;
                else if (w == 1) Ko[(bh * 2048 + s) * 64 + d] = v;
                else             Vt[(bh * 64 + d) * 2048 + s] = v;
            }
        }
    }
}

// ---------------- V suffix tile sums (parallel) ----------------
__global__ __launch_bounds__(256) void tail_kernel(const bf16* __restrict__ Vt,
                                                   float* __restrict__ Tail) {
    const int bh = blockIdx.x;
    const bf16* Vg = Vt + (size_t)bh * 64 * 2048;
    float* Tg = Tail + (size_t)bh * 33 * 64;

    __shared__ float ts[64 * 33];
    const int tid = threadIdx.x;

#pragma unroll
    for (int i = 0; i < 8; ++i) {
        int task = i * 256 + tid;          // 0..2047
        int d = task >> 5, tt = task & 31;
        const bf16* p = &Vg[(size_t)d * 2048 + tt * 64];
        float s = 0.0f;
#pragma unroll
        for (int j = 0; j < 8; ++j) {
            bf16x8 v = *reinterpret_cast<const bf16x8*>(p + j * 8);
#pragma unroll
            for (int e = 0; e < 8; ++e) s += (float)v[e];
        }
        ts[d * 33 + tt] = s;
    }
    __syncthreads();

    if (tid < 64) {
        const int d = tid;
        float s = 0.0f;
        Tg[32 * 64 + d] = 0.0f;
        for (int tt = 31; tt >= 1; --tt) {
            s += ts[d * 33 + tt];
            Tg[tt * 64 + d] = s;
        }
    }
}

// ---------------- attention ----------------
// 128-key chunks (half the barriers). Q pre-scaled by log2(e)/32.
// Multiplicative mask: masked score=0 -> p=exp2(0)=1, still counted — so a fully-masked
// upper half-chunk at the diagonal is handled by the mask itself; Tail starts at 2*np.
__global__ __launch_bounds__(256) void attn_kernel(const bf16* __restrict__ Q,
                                                   const bf16* __restrict__ K,
                                                   const bf16* __restrict__ Vt,
                                                   const float* __restrict__ Tail,
                                                   float* __restrict__ out) {
    const int b = blockIdx.z;
    const int h = blockIdx.y;
    const int j  = ((blockIdx.y >> 3) ^ blockIdx.z) & 1;
    const int qt = j ? (31 - (int)blockIdx.x) : (int)blockIdx.x;
    const int q0 = qt * 64;
    const int np = (qt >> 1) + 1;          // 128-key pairs to process in-loop

    const int t    = threadIdx.x;
    const int lane = t & 63;
    const int wid  = t >> 6;
    const int quad = lane >> 4;
    const int col  = lane & 15;

    const int bh = b * 16 + h;
    const bf16* Qg = Q + (size_t)bh * 2048 * 64;
    const bf16* Kg = K + (size_t)bh * 2048 * 64;
    const bf16* Vg = Vt + (size_t)bh * 64 * 2048;

    __shared__ __align__(16) bf16 Ks[128 * 64];     // 16 KB: [key][d], swizzled
    __shared__ __align__(16) bf16 Vs[64 * 128];     // 16 KB: [d][key], swizzled
    __shared__ __align__(16) bf16 Ps[4 * 16 * 72];  // wave-private P
    bf16* Pw = &Ps[wid * 16 * 72];

    bf16x8 qf[2];
#pragma unroll
    for (int ks = 0; ks < 2; ++ks)
        qf[ks] = *reinterpret_cast<const bf16x8*>(
            &Qg[(size_t)(q0 + wid * 16 + col) * 64 + ks * 32 + quad * 8]);

    bf16x8 ones;
#pragma unroll
    for (int i = 0; i < 8; ++i) ones[i] = (bf16)1.0f;

    // init with fully-masked tail beyond 2*np tiles (p == 1 there)
    f32x4 o[4];
    f32x4 la;
    {
        const float tc = 64.0f * (float)(32 - 2 * np);
#pragma unroll
        for (int r = 0; r < 4; ++r) la[r] = tc;
        const float* Tg = Tail + ((size_t)bh * 33 + 2 * np) * 64;
#pragma unroll
        for (int dt = 0; dt < 4; ++dt) {
            float tv = Tg[dt * 16 + col];
#pragma unroll
            for (int r = 0; r < 4; ++r) o[dt][r] = tv;
        }
    }

    const int qrow = q0 + wid * 16 + quad * 4;
    // K staging: 16 chunk-blocks of 8 rows x 64; V staging: 16 chunk-blocks of 4 rows x 128
    const int rsubK = lane >> 3;
    const int cswK  = ((lane & 7) ^ rsubK) * 8;
    const int rV    = lane >> 4;
    const int ccV   = lane & 15;

    const int s0max = (np - 1) * 128;

    for (int s0 = 0; s0 < np * 128; s0 += 128) {
        __syncthreads();
#pragma unroll
        for (int jj = 0; jj < 4; ++jj) {
            const int c = wid * 4 + jj;
            load_lds16(&Kg[(size_t)(s0 + c * 8 + rsubK) * 64 + cswK], &Ks[c * 512]);
            const int d = c * 4 + rV;
            load_lds16(&Vg[(size_t)d * 2048 + s0 + ((ccV ^ (d & 15)) * 8)], &Vs[c * 512]);
        }
        __syncthreads();

        // S' = (Q*log2e/32) K^T over 8 key-subtiles
        f32x4 sv[8] = {};
#pragma unroll
        for (int ks = 0; ks < 2; ++ks) {
            const int ca = ((ks * 4 + quad) ^ (col & 7)) * 8;
#pragma unroll
            for (int nt = 0; nt < 8; ++nt) {
                bf16x8 kb = *reinterpret_cast<const bf16x8*>(
                    &Ks[(nt * 16 + col) * 64 + ca]);
                sv[nt] = MFMA16(qf[ks], kb, sv[nt]);
            }
        }

        // multiplicative mask only on the last pair (covers diagonal + dead upper half)
        if (s0 == s0max) {
#pragma unroll
            for (int nt = 0; nt < 8; ++nt) {
                int kidx = s0 + nt * 16 + col;
#pragma unroll
                for (int r = 0; r < 4; ++r)
                    if (kidx > qrow + r) sv[nt][r] = 0.0f;
            }
        }

        // PV in two 64-key halves, reusing wave-private Ps
#pragma unroll
        for (int hh = 0; hh < 2; ++hh) {
#pragma unroll
            for (int nt = 0; nt < 4; ++nt)
#pragma unroll
                for (int r = 0; r < 4; ++r)
                    Pw[(quad * 4 + r) * 72 + nt * 16 + col] =
                        (bf16)__builtin_amdgcn_exp2f(sv[hh * 4 + nt][r]);

#pragma unroll
            for (int gg = 0; gg < 2; ++gg) {
                bf16x8 pa = *reinterpret_cast<const bf16x8*>(
                    &Pw[col * 72 + gg * 32 + quad * 8]);
                la = MFMA16(pa, ones, la);
                const int g = hh * 2 + gg;
#pragma unroll
                for (int dt = 0; dt < 4; ++dt) {
                    bf16x8 vb = *reinterpret_cast<const bf16x8*>(
                        &Vs[(dt * 16 + col) * 128 + ((g * 4 + quad) ^ col) * 8]);
                    o[dt] = MFMA16(pa, vb, o[dt]);
                }
            }
        }
    }

#pragma unroll
    for (int r = 0; r < 4; ++r) {
        int q = qrow + r;
        float inv = __builtin_amdgcn_rcpf(la[r]);
#pragma unroll
        for (int dt = 0; dt < 4; ++dt) {
            int d = dt * 16 + col;
            out[((size_t)b * 2048 + q) * 1024 + h * 64 + d] = o[dt][r] * inv;
        }
    }
}

extern "C" void kernel_launch(void* const* d_in, const int* in_sizes, int n_in,
                              void* d_out, int out_size, void* d_ws, size_t ws_size,
                              hipStream_t stream) {
    const float* x  = (const float*)d_in[0];
    const float* Wq = (const float*)d_in[1];
    const float* Wk = (const float*)d_in[2];
    const float* Wv = (const float*)d_in[3];
    float* out = (float*)d_out;

    char* ws = (char*)d_ws;
    bf16*  xb   = (bf16*)(ws);                        // 8 MB
    bf16*  wb   = (bf16*)(ws + (size_t)(8  << 20));   // 6 MB [Wq|Wk|Wv]
    bf16*  Qb   = (bf16*)(ws + (size_t)(14 << 20));   // 8 MB [B,H,S,D] (pre-scaled)
    bf16*  Kb   = (bf16*)(ws + (size_t)(22 << 20));   // 8 MB [B,H,S,D]
    bf16*  Vtb  = (bf16*)(ws + (size_t)(30 << 20));   // 8 MB [B,H,D,S]
    float* Tail = (float*)(ws + (size_t)(38 << 20));  // 264 KB

    const float QSCALE = 1.44269504088896f / 32.0f;   // log2(e)/sqrt(E)

    cast_all<<<7168, 256, 0, stream>>>(x, Wq, Wk, Wv, xb, wb, QSCALE);

    qkv_gemm<<<dim3(48, 32), 256, 0, stream>>>(xb, wb, Qb, Kb, Vtb);

    tail_kernel<<<32, 256, 0, stream>>>(Vtb, Tail);

    attn_kernel<<<dim3(32, 16, 2), 256, 0, stream>>>(Qb, Kb, Vtb, Tail, out);
}